// Round 6
// baseline (1438.316 us; speedup 1.0000x reference)
//
#include <hip/hip_runtime.h>
#include <cstddef>

#define NN 1024
#define DD 6
#define TT 60
#define HH 64
#define NEGV  (-10000.0f)
#define SLOPEV (0.01f)

__device__ __forceinline__ float sig_(float x)  { return 1.0f / (1.0f + __expf(-x)); }
__device__ __forceinline__ float tanh_(float x) { return 1.0f - 2.0f / (__expf(2.0f * x) + 1.0f); }
__device__ __forceinline__ float rl_(float v, int l) {
    return __int_as_float(__builtin_amdgcn_readlane(__float_as_int(v), l));
}

// ---------------------------------------------------------------------------
// k_fused: 256 blocks x 768 threads (12 waves), one block per CU.
//   waves 0-2 : GRU layer-0 (wave = gate, lane = row, 4 samples). Whh0 row +
//               x in registers; h0 lane-distributed, broadcast via v_readlane.
//   waves 3-8 : GRU layer-1 (gate x sample-pair), one step behind.
//   waves 9-11: relation streaming, 1 (i,j) pair / thread / even iter.
// __launch_bounds__(768, 3): 12 waves/CU -> 3 waves/EU -> 170 VGPR cap.
// Live set ~150 regs (wA[64]+wB[64]+hr+acc) fits -> NO SPILL (R5 failed at
// default heuristic VGPR=84 -> 1.1 GB scratch traffic).
// ---------------------------------------------------------------------------
__global__ __launch_bounds__(768, 3)
void k_fused(const float* __restrict__ x, const float* __restrict__ rel,
             const float* __restrict__ W, const float* __restrict__ fc_w,
             const float* __restrict__ Wih0, const float* __restrict__ Whh0,
             const float* __restrict__ bih0, const float* __restrict__ bhh0,
             const float* __restrict__ Wih1, const float* __restrict__ Whh1,
             const float* __restrict__ bih1, const float* __restrict__ bhh1,
             float* __restrict__ sa, float* __restrict__ sb,
             float* __restrict__ hdot, float* __restrict__ hb,
             float* __restrict__ sr, float* __restrict__ ssum)
{
    __shared__ float smem[2048];
    float* Zb   = smem;          // L0 z preact   [s][lane]
    float* Xnb  = smem + 256;    // L0 xn preact
    float* Hnb  = smem + 512;    // L0 hn preact
    float* Z1b  = smem + 768;    // L1 z preact
    float* Xn1b = smem + 1024;   // L1 xn preact
    float* Hn1b = smem + 1280;   // L1 hn preact
    float* H0b  = smem + 1536;   // h0 state      [s][lane]
    float* H1b  = smem + 1792;   // h1 state

    const int tid  = threadIdx.x;
    const int wv   = tid >> 6;
    const int lane = tid & 63;
    const int nb   = blockIdx.x * 4;

    if (tid < 512) smem[1536 + tid] = 0.0f;   // h0 = h1 = 0

    // ---- unioned register state ----
    float wA[64];     // L0: Whh0 row | L1: Wih1 row | rel: Wv[64]
    float wB[64];     // L0: x[4][6] + Wih0 row | L1: Whh1 row | rel: unused
    float hr[4];
    float acc[8];
    float b0 = 0.f, b1 = 0.f;
    unsigned int relp = 0xFFFFFFFFu;

    hr[0] = hr[1] = hr[2] = hr[3] = 0.f;

    if (wv < 3) {
        const int row = wv * 64 + lane;
        #pragma unroll
        for (int q = 0; q < 16; ++q) {
            const float4 v = *(const float4*)(Whh0 + (size_t)row * HH + q * 4);
            wA[4*q] = v.x; wA[4*q+1] = v.y; wA[4*q+2] = v.z; wA[4*q+3] = v.w;
        }
        #pragma unroll
        for (int s = 0; s < 4; ++s)
            #pragma unroll
            for (int d = 0; d < DD; ++d)
                wB[s*6+d] = (lane < TT) ? x[(size_t)(nb + s) * DD * TT + d * TT + lane] : 0.f;
        #pragma unroll
        for (int d = 0; d < DD; ++d) wB[24 + d] = Wih0[row * DD + d];
        b0 = bih0[row]; b1 = bhh0[row];
    } else if (wv < 9) {
        const int u = wv - 3, g1 = u >> 1;
        const int row = g1 * 64 + lane;
        #pragma unroll
        for (int q = 0; q < 16; ++q) {
            const float4 a = *(const float4*)(Wih1 + (size_t)row * HH + q * 4);
            wA[4*q] = a.x; wA[4*q+1] = a.y; wA[4*q+2] = a.z; wA[4*q+3] = a.w;
            const float4 c = *(const float4*)(Whh1 + (size_t)row * HH + q * 4);
            wB[4*q] = c.x; wB[4*q+1] = c.y; wB[4*q+2] = c.z; wB[4*q+3] = c.w;
        }
        b0 = bih1[row]; b1 = bhh1[row];
    } else {
        #pragma unroll
        for (int q = 0; q < 64; ++q) wA[q] = W[2 * HH + q];
        relp = blockIdx.x * 192 + (tid - 576);      // 0..49151
    }
    __syncthreads();

    for (int i = 0; i <= TT; ++i) {
        // ---------------- phase 1: MM / rel ----------------
        if (wv < 3) {
            if (i < TT) {
                #pragma unroll
                for (int s = 0; s < 4; ++s) { acc[s] = b1; acc[4 + s] = b0; }
                #pragma unroll
                for (int k = 0; k < 64; ++k) {
                    const float wk = wA[k];
                    acc[0] += rl_(hr[0], k) * wk;
                    acc[1] += rl_(hr[1], k) * wk;
                    acc[2] += rl_(hr[2], k) * wk;
                    acc[3] += rl_(hr[3], k) * wk;
                }
                #pragma unroll
                for (int d = 0; d < DD; ++d) {
                    const float wd = wB[24 + d];
                    acc[4] += rl_(wB[0*6+d], i) * wd;
                    acc[5] += rl_(wB[1*6+d], i) * wd;
                    acc[6] += rl_(wB[2*6+d], i) * wd;
                    acc[7] += rl_(wB[3*6+d], i) * wd;
                }
                if (wv == 1) {
                    #pragma unroll
                    for (int s = 0; s < 4; ++s) Zb[s*64+lane] = acc[s] + acc[4+s];
                } else if (wv == 2) {
                    #pragma unroll
                    for (int s = 0; s < 4; ++s) { Xnb[s*64+lane] = acc[4+s]; Hnb[s*64+lane] = acc[s]; }
                }
                // wv==0 keeps r preact in acc
            }
        } else if (wv < 9) {
            if (i >= 1) {
                const int u = wv - 3, g1 = u >> 1, p = u & 1;
                acc[0] = b1; acc[1] = b1; acc[4] = b0; acc[5] = b0;
                #pragma unroll
                for (int k = 0; k < 64; ++k) {
                    const float wa = wA[k], wc = wB[k];
                    acc[4] += rl_(hr[0], k) * wa;   // Wih1 . h0
                    acc[5] += rl_(hr[1], k) * wa;
                    acc[0] += rl_(hr[2], k) * wc;   // Whh1 . h1
                    acc[1] += rl_(hr[3], k) * wc;
                }
                if (g1 == 1) {
                    Z1b[(2*p+0)*64+lane] = acc[0] + acc[4];
                    Z1b[(2*p+1)*64+lane] = acc[1] + acc[5];
                } else if (g1 == 2) {
                    Xn1b[(2*p+0)*64+lane] = acc[4]; Hn1b[(2*p+0)*64+lane] = acc[0];
                    Xn1b[(2*p+1)*64+lane] = acc[5]; Hn1b[(2*p+1)*64+lane] = acc[1];
                }
            }
        } else {
            if ((i & 1) == 0 && relp < (unsigned)(NN * NN)) {
                // two 8x float4 chunks: 8 loads in flight, ~32 staging regs
                const float4* base = (const float4*)(rel + (size_t)relp * 64);
                float d0 = 0.f, d1 = 0.f, s0 = 0.f, s1 = 0.f;
                #pragma unroll
                for (int c = 0; c < 2; ++c) {
                    float4 v[8];
                    #pragma unroll
                    for (int q = 0; q < 8; ++q) v[q] = base[c * 8 + q];
                    #pragma unroll
                    for (int q = 0; q < 8; ++q) {
                        const int kk = (c * 8 + q) * 4;
                        d0 += v[q].x * wA[kk]   + v[q].z * wA[kk+2];
                        d1 += v[q].y * wA[kk+1] + v[q].w * wA[kk+3];
                        s0 += v[q].x + v[q].z;
                        s1 += v[q].y + v[q].w;
                    }
                }
                sr[relp]   = d0 + d1;
                ssum[relp] = s0 + s1;
                relp += 49152;
            }
        }
        __syncthreads();

        // ---------------- phase 2: activations ----------------
        if (wv == 0 && i < TT) {
            #pragma unroll
            for (int s = 0; s < 4; ++s) {
                const float r  = sig_(acc[s] + acc[4+s]);
                const float z  = sig_(Zb[s*64+lane]);
                const float hn = Hnb[s*64+lane];
                const float nv = tanh_(Xnb[s*64+lane] + r * hn);
                H0b[s*64+lane] = (1.f - z) * nv + z * hr[s];
            }
        }
        if ((wv == 3 || wv == 4) && i >= 1) {
            const int p = wv - 3;
            #pragma unroll
            for (int ss = 0; ss < 2; ++ss) {
                const int s = 2*p + ss;
                const float r1  = sig_(acc[ss] + acc[4+ss]);
                const float z1  = sig_(Z1b[s*64+lane]);
                const float hn1 = Hn1b[s*64+lane];
                const float nv1 = tanh_(Xn1b[s*64+lane] + r1 * hn1);
                H1b[s*64+lane] = (1.f - z1) * nv1 + z1 * hr[2+ss];
            }
        }
        __syncthreads();

        // ---------------- refresh lane-distributed state ----------------
        if (wv < 3) {
            #pragma unroll
            for (int s = 0; s < 4; ++s) hr[s] = H0b[s*64+lane];
        } else if (wv < 9) {
            const int p = (wv - 3) & 1;
            hr[0] = H0b[(2*p+0)*64+lane];
            hr[1] = H0b[(2*p+1)*64+lane];
            hr[2] = H1b[(2*p+0)*64+lane];
            hr[3] = H1b[(2*p+1)*64+lane];
        }
    }

    // ---------------- epilogue: per-sample scalars (wave 0) ----------------
    if (wv == 0) {
        #pragma unroll
        for (int s = 0; s < 4; ++s) {
            const float hv = H1b[s*64+lane];
            float pa = hv * W[lane];
            float pb = hv * W[HH + lane];
            float pc = hv * fc_w[lane];
            float pd = hv * fc_w[HH + lane];
            #pragma unroll
            for (int off = 32; off >= 1; off >>= 1) {
                pa += __shfl_down(pa, off);
                pb += __shfl_down(pb, off);
                pc += __shfl_down(pc, off);
                pd += __shfl_down(pd, off);
            }
            if (lane == 0) {
                sa[nb + s] = pa; sb[nb + s] = pb;
                hdot[nb + s] = pc; hb[nb + s] = pd;
            }
        }
    }
}

// ---------------------------------------------------------------------------
// k2: per row i — masked leaky scores, exact masked-softmax semantics,
// out_i = hdot_i + (sum_j e_j*m_j*hb_j)/denom + fc_b.
// ---------------------------------------------------------------------------
__global__ __launch_bounds__(256)
void k2(const float* __restrict__ sa, const float* __restrict__ sb,
        const float* __restrict__ hdot, const float* __restrict__ hb,
        const float* __restrict__ sr, const float* __restrict__ ssum,
        const float* __restrict__ bscal, const float* __restrict__ fc_b,
        float* __restrict__ out)
{
    __shared__ float red[12];
    const int i   = blockIdx.x;
    const int tid = threadIdx.x;
    const int j4  = tid * 4;
    const float sai = sa[i] + bscal[0];

    const float4 srv = *(const float4*)(sr   + (size_t)i * NN + j4);
    const float4 ssv = *(const float4*)(ssum + (size_t)i * NN + j4);
    const float4 sbv = *(const float4*)(sb + j4);

    float tv[4], mk[4];
    float mloc = -3.4e38f;
    {
        const float srq[4] = {srv.x, srv.y, srv.z, srv.w};
        const float ssq[4] = {ssv.x, ssv.y, ssv.z, ssv.w};
        const float sbq[4] = {sbv.x, sbv.y, sbv.z, sbv.w};
        #pragma unroll
        for (int q = 0; q < 4; ++q) {
            float w = sai + sbq[q] + srq[q];
            w = (w >= 0.0f) ? w : SLOPEV * w;
            const float m = (ssq[q] != 0.0f) ? 1.0f : 0.0f;
            float t = m * w;
            t = (t == 0.0f) ? NEGV : t;
            tv[q] = t; mk[q] = m;
            mloc = fmaxf(mloc, t);
        }
    }
    #pragma unroll
    for (int off = 32; off >= 1; off >>= 1) mloc = fmaxf(mloc, __shfl_xor(mloc, off));
    if ((tid & 63) == 0) red[tid >> 6] = mloc;
    __syncthreads();
    const float mx = fmaxf(fmaxf(red[0], red[1]), fmaxf(red[2], red[3]));

    const float4 hbv = *(const float4*)(hb + j4);
    const float hbq[4] = {hbv.x, hbv.y, hbv.z, hbv.w};
    float sloc = 0.0f, vloc = 0.0f;
    #pragma unroll
    for (int q = 0; q < 4; ++q) {
        const float e = __expf(tv[q] - mx);   // masked -> exp(-1e4 - mx) == 0
        sloc += e;
        vloc += e * mk[q] * hbq[q];
    }
    #pragma unroll
    for (int off = 32; off >= 1; off >>= 1) {
        sloc += __shfl_xor(sloc, off);
        vloc += __shfl_xor(vloc, off);
    }
    if ((tid & 63) == 0) { red[4 + (tid >> 6)] = sloc; red[8 + (tid >> 6)] = vloc; }
    __syncthreads();
    if (tid == 0) {
        const float denom = red[4] + red[5] + red[6] + red[7];
        const float vsum  = red[8] + red[9] + red[10] + red[11];
        out[i] = hdot[i] + vsum / denom + fc_b[0];
    }
}

// ---------------------------------------------------------------------------
extern "C" void kernel_launch(void* const* d_in, const int* in_sizes, int n_in,
                              void* d_out, int out_size, void* d_ws, size_t ws_size,
                              hipStream_t stream)
{
    const float* x     = (const float*)d_in[0];
    const float* rel   = (const float*)d_in[1];
    const float* W     = (const float*)d_in[2];
    const float* b     = (const float*)d_in[3];
    const float* fc_w  = (const float*)d_in[4];
    const float* fc_b  = (const float*)d_in[5];
    const float* Wih0  = (const float*)d_in[6];
    const float* Whh0  = (const float*)d_in[7];
    const float* bih0  = (const float*)d_in[8];
    const float* bhh0  = (const float*)d_in[9];
    const float* Wih1  = (const float*)d_in[10];
    const float* Whh1  = (const float*)d_in[11];
    const float* bih1  = (const float*)d_in[12];
    const float* bhh1  = (const float*)d_in[13];

    float* ws   = (float*)d_ws;
    float* sa   = ws;                         // 1024
    float* sb   = sa   + NN;                  // 1024
    float* hdot = sb   + NN;                  // 1024
    float* hb   = hdot + NN;                  // 1024
    float* sr   = hb   + NN;                  // 1024*1024
    float* ssum = sr   + (size_t)NN * NN;     // 1024*1024

    k_fused<<<256, 768, 0, stream>>>(x, rel, W, fc_w,
                                     Wih0, Whh0, bih0, bhh0,
                                     Wih1, Whh1, bih1, bhh1,
                                     sa, sb, hdot, hb, sr, ssum);
    k2<<<NN, 256, 0, stream>>>(sa, sb, hdot, hb, sr, ssum,
                               b, fc_b, (float*)d_out);
}

// Round 7
// 784.742 us; speedup vs baseline: 1.8329x; 1.8329x over previous
//
#include <hip/hip_runtime.h>
#include <cstddef>

#define NN 1024
#define DD 6
#define TT 60
#define HH 64
#define NEGV  (-10000.0f)
#define SLOPEV (0.01f)

__device__ __forceinline__ float sig_(float x)  { return 1.0f / (1.0f + __expf(-x)); }
__device__ __forceinline__ float tanh_(float x) { return 1.0f - 2.0f / (__expf(2.0f * x) + 1.0f); }
__device__ __forceinline__ float rl_(float v, int l) {
    return __int_as_float(__builtin_amdgcn_readlane(__float_as_int(v), l));
}

// ---------------------------------------------------------------------------
// k_fused: 256 blocks x 768 threads (12 waves), one block per CU.
//   waves 0-2 : GRU layer-0; wave = gate (r,z,n), lane = gate row, 4 samples.
//               Whh0 row (64) + Wih0 row (6) in regs, x lane-distributed (24),
//               h0 broadcast via v_readlane. Wave 0 also does L0 activations.
//   waves 3-8 : GRU layer-1, one step behind; wave = (gate g, matrix m):
//               m=0: Wih1 row . h0prev, m=1: Whh1 row . h1prev — only 64
//               weight floats/thread; partials meet in LDS P[6][4][64].
//               Waves 3,4 do L1 activations (2 samples each).
//   waves 9-11: relation streaming, 1 (i,j) pair/thread/even iter.
// amdgpu_waves_per_eu(3,3): pins 12 waves/CU -> 168-VGPR budget. R6 showed
// __launch_bounds__(768,3) is ignored (VGPR stayed 84 = 2-blocks/CU target).
// ---------------------------------------------------------------------------
__global__ __launch_bounds__(768)
__attribute__((amdgpu_waves_per_eu(3, 3)))
void k_fused(const float* __restrict__ x, const float* __restrict__ rel,
             const float* __restrict__ W, const float* __restrict__ fc_w,
             const float* __restrict__ Wih0, const float* __restrict__ Whh0,
             const float* __restrict__ bih0, const float* __restrict__ bhh0,
             const float* __restrict__ Wih1, const float* __restrict__ Whh1,
             const float* __restrict__ bih1, const float* __restrict__ bhh1,
             float* __restrict__ sa, float* __restrict__ sb,
             float* __restrict__ hdot, float* __restrict__ hb,
             float* __restrict__ sr, float* __restrict__ ssum)
{
    __shared__ float smem[2816];
    float* Zb  = smem;           // [s][lane] L0 z preact
    float* Xnb = smem + 256;     // L0 xn preact
    float* Hnb = smem + 512;     // L0 hn preact
    float* P   = smem + 768;     // [u][s][lane] L1 partials, u = g*2+m
    float* H0b = smem + 2304;    // h0 state [s][lane]
    float* H1b = smem + 2560;    // h1 state

    const int tid  = threadIdx.x;
    const int wv   = tid >> 6;
    const int lane = tid & 63;
    const int nb   = blockIdx.x * 4;

    if (tid < 512) smem[2304 + tid] = 0.0f;   // h0 = h1 = 0

    float wA[64];          // L0: Whh0 row | L1: (m? Whh1 : Wih1) row | rel: Wv
    float xlane[24];       // L0 only: x[s][d] at lane = t
    float wi0[DD];         // L0 only
    float hr[4];           // lane-distributed state
    float acc[4];
    float b0 = 0.f, b1 = 0.f;
    unsigned int relp = 0xFFFFFFFFu;
    int g1 = 0, m1 = 0;

    hr[0] = hr[1] = hr[2] = hr[3] = 0.f;

    if (wv < 3) {
        const int row = wv * 64 + lane;
        #pragma unroll
        for (int q = 0; q < 16; ++q) {
            const float4 v = *(const float4*)(Whh0 + (size_t)row * HH + q * 4);
            wA[4*q] = v.x; wA[4*q+1] = v.y; wA[4*q+2] = v.z; wA[4*q+3] = v.w;
        }
        #pragma unroll
        for (int s = 0; s < 4; ++s)
            #pragma unroll
            for (int d = 0; d < DD; ++d)
                xlane[s*6+d] = (lane < TT) ? x[(size_t)(nb + s) * DD * TT + d * TT + lane] : 0.f;
        #pragma unroll
        for (int d = 0; d < DD; ++d) wi0[d] = Wih0[row * DD + d];
        b0 = bih0[row]; b1 = bhh0[row];
    } else if (wv < 9) {
        const int u = wv - 3;
        g1 = u >> 1; m1 = u & 1;
        const int row = g1 * 64 + lane;
        const float* Wm = m1 ? Whh1 : Wih1;
        #pragma unroll
        for (int q = 0; q < 16; ++q) {
            const float4 v = *(const float4*)(Wm + (size_t)row * HH + q * 4);
            wA[4*q] = v.x; wA[4*q+1] = v.y; wA[4*q+2] = v.z; wA[4*q+3] = v.w;
        }
        b0 = m1 ? bhh1[row] : bih1[row];
    } else {
        #pragma unroll
        for (int q = 0; q < 64; ++q) wA[q] = W[2 * HH + q];
        relp = blockIdx.x * 192 + (tid - 576);      // 0..49151
    }
    __syncthreads();

    for (int i = 0; i <= TT; ++i) {
        // ---------------- phase 1: matrix products / rel ----------------
        if (wv < 3) {
            if (i < TT) {
                float hg[4], xg[4];
                #pragma unroll
                for (int s = 0; s < 4; ++s) { hg[s] = b1; xg[s] = b0; }
                #pragma unroll
                for (int k = 0; k < 64; ++k) {
                    const float wk = wA[k];
                    hg[0] += rl_(hr[0], k) * wk;
                    hg[1] += rl_(hr[1], k) * wk;
                    hg[2] += rl_(hr[2], k) * wk;
                    hg[3] += rl_(hr[3], k) * wk;
                }
                #pragma unroll
                for (int d = 0; d < DD; ++d) {
                    const float wd = wi0[d];
                    xg[0] += rl_(xlane[0*6+d], i) * wd;
                    xg[1] += rl_(xlane[1*6+d], i) * wd;
                    xg[2] += rl_(xlane[2*6+d], i) * wd;
                    xg[3] += rl_(xlane[3*6+d], i) * wd;
                }
                if (wv == 0) {
                    #pragma unroll
                    for (int s = 0; s < 4; ++s) acc[s] = xg[s] + hg[s];   // r preact
                } else if (wv == 1) {
                    #pragma unroll
                    for (int s = 0; s < 4; ++s) Zb[s*64+lane] = xg[s] + hg[s];
                } else {
                    #pragma unroll
                    for (int s = 0; s < 4; ++s) { Xnb[s*64+lane] = xg[s]; Hnb[s*64+lane] = hg[s]; }
                }
            }
        } else if (wv < 9) {
            if (i >= 1) {
                #pragma unroll
                for (int s = 0; s < 4; ++s) acc[s] = b0;
                #pragma unroll
                for (int k = 0; k < 64; ++k) {
                    const float wk = wA[k];
                    acc[0] += rl_(hr[0], k) * wk;
                    acc[1] += rl_(hr[1], k) * wk;
                    acc[2] += rl_(hr[2], k) * wk;
                    acc[3] += rl_(hr[3], k) * wk;
                }
                const int u = wv - 3;
                #pragma unroll
                for (int s = 0; s < 4; ++s) P[(u*4 + s)*64 + lane] = acc[s];
            }
        } else {
            if ((i & 1) == 0 && relp < (unsigned)(NN * NN)) {
                const float4* base = (const float4*)(rel + (size_t)relp * 64);
                float d0 = 0.f, d1 = 0.f, s0 = 0.f, s1 = 0.f;
                #pragma unroll
                for (int c = 0; c < 2; ++c) {
                    float4 v[8];
                    #pragma unroll
                    for (int q = 0; q < 8; ++q) v[q] = base[c * 8 + q];
                    #pragma unroll
                    for (int q = 0; q < 8; ++q) {
                        const int kk = (c * 8 + q) * 4;
                        d0 += v[q].x * wA[kk]   + v[q].z * wA[kk+2];
                        d1 += v[q].y * wA[kk+1] + v[q].w * wA[kk+3];
                        s0 += v[q].x + v[q].z;
                        s1 += v[q].y + v[q].w;
                    }
                }
                sr[relp]   = d0 + d1;
                ssum[relp] = s0 + s1;
                relp += 49152;
            }
        }
        __syncthreads();

        // ---------------- phase 2: activations ----------------
        if (wv == 0 && i < TT) {
            #pragma unroll
            for (int s = 0; s < 4; ++s) {
                const float r  = sig_(acc[s]);
                const float z  = sig_(Zb[s*64+lane]);
                const float hn = Hnb[s*64+lane];
                const float nv = tanh_(Xnb[s*64+lane] + r * hn);
                H0b[s*64+lane] = (1.f - z) * nv + z * hr[s];
            }
        }
        if ((wv == 3 || wv == 4) && i >= 1) {
            const int sbase = (wv - 3) * 2;
            #pragma unroll
            for (int ss = 0; ss < 2; ++ss) {
                const int s = sbase + ss;
                const float r1  = sig_(P[(0*4+s)*64+lane] + P[(1*4+s)*64+lane]);
                const float z1  = sig_(P[(2*4+s)*64+lane] + P[(3*4+s)*64+lane]);
                const float hn1 = P[(5*4+s)*64+lane];
                const float nv1 = tanh_(P[(4*4+s)*64+lane] + r1 * hn1);
                const float hprev = H1b[s*64+lane];
                H1b[s*64+lane] = (1.f - z1) * nv1 + z1 * hprev;
            }
        }
        __syncthreads();

        // ---------------- refresh lane-distributed state ----------------
        if (wv < 3) {
            #pragma unroll
            for (int s = 0; s < 4; ++s) hr[s] = H0b[s*64+lane];
        } else if (wv < 9) {
            const float* src = m1 ? H1b : H0b;
            #pragma unroll
            for (int s = 0; s < 4; ++s) hr[s] = src[s*64+lane];
        }
    }

    // ---------------- epilogue: per-sample scalars (wave 0) ----------------
    if (wv == 0) {
        #pragma unroll
        for (int s = 0; s < 4; ++s) {
            const float hv = H1b[s*64+lane];
            float pa = hv * W[lane];
            float pb = hv * W[HH + lane];
            float pc = hv * fc_w[lane];
            float pd = hv * fc_w[HH + lane];
            #pragma unroll
            for (int off = 32; off >= 1; off >>= 1) {
                pa += __shfl_down(pa, off);
                pb += __shfl_down(pb, off);
                pc += __shfl_down(pc, off);
                pd += __shfl_down(pd, off);
            }
            if (lane == 0) {
                sa[nb + s] = pa; sb[nb + s] = pb;
                hdot[nb + s] = pc; hb[nb + s] = pd;
            }
        }
    }
}

// ---------------------------------------------------------------------------
// k2: per row i — masked leaky scores, exact masked-softmax semantics,
// out_i = hdot_i + (sum_j e_j*m_j*hb_j)/denom + fc_b.
// ---------------------------------------------------------------------------
__global__ __launch_bounds__(256)
void k2(const float* __restrict__ sa, const float* __restrict__ sb,
        const float* __restrict__ hdot, const float* __restrict__ hb,
        const float* __restrict__ sr, const float* __restrict__ ssum,
        const float* __restrict__ bscal, const float* __restrict__ fc_b,
        float* __restrict__ out)
{
    __shared__ float red[12];
    const int i   = blockIdx.x;
    const int tid = threadIdx.x;
    const int j4  = tid * 4;
    const float sai = sa[i] + bscal[0];

    const float4 srv = *(const float4*)(sr   + (size_t)i * NN + j4);
    const float4 ssv = *(const float4*)(ssum + (size_t)i * NN + j4);
    const float4 sbv = *(const float4*)(sb + j4);

    float tv[4], mk[4];
    float mloc = -3.4e38f;
    {
        const float srq[4] = {srv.x, srv.y, srv.z, srv.w};
        const float ssq[4] = {ssv.x, ssv.y, ssv.z, ssv.w};
        const float sbq[4] = {sbv.x, sbv.y, sbv.z, sbv.w};
        #pragma unroll
        for (int q = 0; q < 4; ++q) {
            float w = sai + sbq[q] + srq[q];
            w = (w >= 0.0f) ? w : SLOPEV * w;
            const float m = (ssq[q] != 0.0f) ? 1.0f : 0.0f;
            float t = m * w;
            t = (t == 0.0f) ? NEGV : t;
            tv[q] = t; mk[q] = m;
            mloc = fmaxf(mloc, t);
        }
    }
    #pragma unroll
    for (int off = 32; off >= 1; off >>= 1) mloc = fmaxf(mloc, __shfl_xor(mloc, off));
    if ((tid & 63) == 0) red[tid >> 6] = mloc;
    __syncthreads();
    const float mx = fmaxf(fmaxf(red[0], red[1]), fmaxf(red[2], red[3]));

    const float4 hbv = *(const float4*)(hb + j4);
    const float hbq[4] = {hbv.x, hbv.y, hbv.z, hbv.w};
    float sloc = 0.0f, vloc = 0.0f;
    #pragma unroll
    for (int q = 0; q < 4; ++q) {
        const float e = __expf(tv[q] - mx);   // masked -> exp(-1e4 - mx) == 0
        sloc += e;
        vloc += e * mk[q] * hbq[q];
    }
    #pragma unroll
    for (int off = 32; off >= 1; off >>= 1) {
        sloc += __shfl_xor(sloc, off);
        vloc += __shfl_xor(vloc, off);
    }
    if ((tid & 63) == 0) { red[4 + (tid >> 6)] = sloc; red[8 + (tid >> 6)] = vloc; }
    __syncthreads();
    if (tid == 0) {
        const float denom = red[4] + red[5] + red[6] + red[7];
        const float vsum  = red[8] + red[9] + red[10] + red[11];
        out[i] = hdot[i] + vsum / denom + fc_b[0];
    }
}

// ---------------------------------------------------------------------------
extern "C" void kernel_launch(void* const* d_in, const int* in_sizes, int n_in,
                              void* d_out, int out_size, void* d_ws, size_t ws_size,
                              hipStream_t stream)
{
    const float* x     = (const float*)d_in[0];
    const float* rel   = (const float*)d_in[1];
    const float* W     = (const float*)d_in[2];
    const float* b     = (const float*)d_in[3];
    const float* fc_w  = (const float*)d_in[4];
    const float* fc_b  = (const float*)d_in[5];
    const float* Wih0  = (const float*)d_in[6];
    const float* Whh0  = (const float*)d_in[7];
    const float* bih0  = (const float*)d_in[8];
    const float* bhh0  = (const float*)d_in[9];
    const float* Wih1  = (const float*)d_in[10];
    const float* Whh1  = (const float*)d_in[11];
    const float* bih1  = (const float*)d_in[12];
    const float* bhh1  = (const float*)d_in[13];

    float* ws   = (float*)d_ws;
    float* sa   = ws;                         // 1024
    float* sb   = sa   + NN;                  // 1024
    float* hdot = sb   + NN;                  // 1024
    float* hb   = hdot + NN;                  // 1024
    float* sr   = hb   + NN;                  // 1024*1024
    float* ssum = sr   + (size_t)NN * NN;     // 1024*1024

    k_fused<<<256, 768, 0, stream>>>(x, rel, W, fc_w,
                                     Wih0, Whh0, bih0, bhh0,
                                     Wih1, Whh1, bih1, bhh1,
                                     sa, sb, hdot, hb, sr, ssum);
    k2<<<NN, 256, 0, stream>>>(sa, sb, hdot, hb, sr, ssum,
                               b, fc_b, (float*)d_out);
}

// Round 8
// 552.503 us; speedup vs baseline: 2.6033x; 1.4203x over previous
//
#include <hip/hip_runtime.h>
#include <cstddef>

#define NN 1024
#define DD 6
#define TT 60
#define HH 64
#define NEGV  (-10000.0f)
#define SLOPEV (0.01f)

__device__ __forceinline__ float sig_(float x)  { return 1.0f / (1.0f + __expf(-x)); }
__device__ __forceinline__ float tanh_(float x) { return 1.0f - 2.0f / (__expf(2.0f * x) + 1.0f); }
__device__ __forceinline__ float rl_(float v, int l) {
    return __int_as_float(__builtin_amdgcn_readlane(__float_as_int(v), l));
}

__device__ __forceinline__ void rel_pair(const float* __restrict__ rel,
                                         const float* __restrict__ Wv,
                                         float* __restrict__ sr,
                                         float* __restrict__ ssum,
                                         unsigned int relp)
{
    const float4* base = (const float4*)(rel + (size_t)relp * 64);
    float d0 = 0.f, d1 = 0.f, s0 = 0.f, s1 = 0.f;
    #pragma unroll
    for (int c = 0; c < 2; ++c) {
        float4 v[8];
        #pragma unroll
        for (int q = 0; q < 8; ++q) v[q] = base[c * 8 + q];   // 8 loads in flight
        #pragma unroll
        for (int q = 0; q < 8; ++q) {
            const float4 wq = ((const float4*)Wv)[c * 8 + q]; // LDS broadcast (free)
            d0 += v[q].x * wq.x + v[q].z * wq.z;
            d1 += v[q].y * wq.y + v[q].w * wq.w;
            s0 += v[q].x + v[q].z;
            s1 += v[q].y + v[q].w;
        }
    }
    sr[relp]   = d0 + d1;
    ssum[relp] = s0 + s1;
}

// ---------------------------------------------------------------------------
// k_fused: 256 blocks x 768 threads (12 waves), ~1 block/CU.
//   waves 0-2 : GRU L0; wave = gate, lane = row, 4 samples. Whh0 from LDS
//               (transposed: WT0[k*192+row], conflict-free ds_read_b32/k);
//               x (24) + Wih0 row (6) live in wreg. h0 bcast via v_readlane.
//   waves 3-8 : GRU L1, (gate g, matrix m), one step behind. The single
//               64-float matrix row lives in wreg; partials meet in LDS P.
//   waves 9-11: relation streaming, 1 pair / thread / (i%3==0) slot + tail.
// KEY (R5/R6/R7 lesson): VGPR stuck at 84; role-specific arrays' live ranges
// overlap the loop, so ALL roles share ONE 64-float array -> live set <=80,
// no spill at 84. L0's former 94-reg set is split LDS(64)+wreg(30).
// ---------------------------------------------------------------------------
__global__ __launch_bounds__(768)
void k_fused(const float* __restrict__ x, const float* __restrict__ rel,
             const float* __restrict__ W, const float* __restrict__ fc_w,
             const float* __restrict__ Wih0, const float* __restrict__ Whh0,
             const float* __restrict__ bih0, const float* __restrict__ bhh0,
             const float* __restrict__ Wih1, const float* __restrict__ Whh1,
             const float* __restrict__ bih1, const float* __restrict__ bhh1,
             float* __restrict__ sa, float* __restrict__ sb,
             float* __restrict__ hdot, float* __restrict__ hb,
             float* __restrict__ sr, float* __restrict__ ssum)
{
    __shared__ float smem[15168];                // 60.7 KB
    float* WT0 = smem;            // [k][row] Whh0 transposed, 64*192
    float* Wv  = smem + 12288;    // 64
    float* Zb  = smem + 12352;    // [s][lane] L0 z preact
    float* Xnb = smem + 12608;    // L0 xn preact
    float* Hnb = smem + 12864;    // L0 hn preact
    float* P   = smem + 13120;    // [u][s][lane], u = g*2+m
    float* H0b = smem + 14656;    // h0 state
    float* H1b = smem + 14912;    // h1 state

    const int tid  = threadIdx.x;
    const int wv   = tid >> 6;
    const int lane = tid & 63;
    const int nb   = blockIdx.x * 4;

    // ---- stage Whh0 transposed (LDS conflict-free; global rides L2) ----
    for (int idx = tid; idx < 192 * 64; idx += 768) {
        const int k   = idx / 192;
        const int row = idx - k * 192;
        WT0[idx] = Whh0[row * 64 + k];
    }
    if (tid < 64) Wv[tid] = W[2 * HH + tid];
    if (tid < 512) smem[14656 + tid] = 0.0f;     // h0 = h1 = 0

    // ---- ONE shared persistent array per thread (<=64 floats) ----
    float wreg[64];
    float hr[4];
    float b0 = 0.f, b1 = 0.f;
    unsigned int relp = 0xFFFFFFFFu;
    int m1 = 0, wrow = 0;

    hr[0] = hr[1] = hr[2] = hr[3] = 0.f;

    if (wv < 3) {
        wrow = wv * 64 + lane;
        #pragma unroll
        for (int s = 0; s < 4; ++s)
            #pragma unroll
            for (int d = 0; d < DD; ++d)
                wreg[s * 6 + d] = (lane < TT) ? x[(size_t)(nb + s) * DD * TT + d * TT + lane] : 0.f;
        #pragma unroll
        for (int d = 0; d < DD; ++d) wreg[24 + d] = Wih0[wrow * DD + d];
        b0 = bih0[wrow]; b1 = bhh0[wrow];
    } else if (wv < 9) {
        const int u = wv - 3;
        m1 = u & 1;
        const int row = (u >> 1) * 64 + lane;
        const float* Wm = m1 ? Whh1 : Wih1;
        #pragma unroll
        for (int q = 0; q < 16; ++q) {
            const float4 v = *(const float4*)(Wm + (size_t)row * HH + q * 4);
            wreg[4*q] = v.x; wreg[4*q+1] = v.y; wreg[4*q+2] = v.z; wreg[4*q+3] = v.w;
        }
        b0 = m1 ? bhh1[row] : bih1[row];
    } else {
        relp = blockIdx.x * 192 + (tid - 576);   // 0..49151
    }
    __syncthreads();

    for (int i = 0; i <= TT; ++i) {
        float racc0 = 0.f, racc1 = 0.f, racc2 = 0.f, racc3 = 0.f;  // iteration-local

        // ---------------- phase 1: matrix products / rel ----------------
        if (wv < 3) {
            if (i < TT) {
                float hg0 = b1, hg1 = b1, hg2 = b1, hg3 = b1;
                float xg0 = b0, xg1 = b0, xg2 = b0, xg3 = b0;
                const float* wt = WT0 + wrow;
                #pragma unroll
                for (int k = 0; k < 64; ++k) {
                    const float wk = wt[k * 192];          // ds_read_b32, no conflict
                    hg0 += rl_(hr[0], k) * wk;
                    hg1 += rl_(hr[1], k) * wk;
                    hg2 += rl_(hr[2], k) * wk;
                    hg3 += rl_(hr[3], k) * wk;
                }
                #pragma unroll
                for (int d = 0; d < DD; ++d) {
                    const float wd = wreg[24 + d];
                    xg0 += rl_(wreg[0*6+d], i) * wd;
                    xg1 += rl_(wreg[1*6+d], i) * wd;
                    xg2 += rl_(wreg[2*6+d], i) * wd;
                    xg3 += rl_(wreg[3*6+d], i) * wd;
                }
                if (wv == 0) {
                    racc0 = xg0 + hg0; racc1 = xg1 + hg1;
                    racc2 = xg2 + hg2; racc3 = xg3 + hg3;
                } else if (wv == 1) {
                    Zb[0*64+lane] = xg0 + hg0; Zb[1*64+lane] = xg1 + hg1;
                    Zb[2*64+lane] = xg2 + hg2; Zb[3*64+lane] = xg3 + hg3;
                } else {
                    Xnb[0*64+lane] = xg0; Xnb[1*64+lane] = xg1;
                    Xnb[2*64+lane] = xg2; Xnb[3*64+lane] = xg3;
                    Hnb[0*64+lane] = hg0; Hnb[1*64+lane] = hg1;
                    Hnb[2*64+lane] = hg2; Hnb[3*64+lane] = hg3;
                }
            }
        } else if (wv < 9) {
            if (i >= 1) {
                float a0 = b0, a1 = b0, a2 = b0, a3 = b0;
                #pragma unroll
                for (int k = 0; k < 64; ++k) {
                    const float wk = wreg[k];
                    a0 += rl_(hr[0], k) * wk;
                    a1 += rl_(hr[1], k) * wk;
                    a2 += rl_(hr[2], k) * wk;
                    a3 += rl_(hr[3], k) * wk;
                }
                const int u = wv - 3;
                P[u*256 + 0*64 + lane] = a0;
                P[u*256 + 1*64 + lane] = a1;
                P[u*256 + 2*64 + lane] = a2;
                P[u*256 + 3*64 + lane] = a3;
            }
        } else {
            if ((i % 3 == 0) && relp < (unsigned)(NN * NN)) {
                rel_pair(rel, Wv, sr, ssum, relp);
                relp += 49152;
            }
        }
        __syncthreads();

        // ---------------- phase 2: activations ----------------
        if (wv == 0 && i < TT) {
            const float ra[4] = {racc0, racc1, racc2, racc3};
            #pragma unroll
            for (int s = 0; s < 4; ++s) {
                const float r  = sig_(ra[s]);
                const float z  = sig_(Zb[s*64+lane]);
                const float hn = Hnb[s*64+lane];
                const float nv = tanh_(Xnb[s*64+lane] + r * hn);
                H0b[s*64+lane] = (1.f - z) * nv + z * hr[s];
            }
        }
        if ((wv == 3 || wv == 4) && i >= 1) {
            const int sbase = (wv - 3) * 2;
            #pragma unroll
            for (int ss = 0; ss < 2; ++ss) {
                const int s = sbase + ss;
                const float r1  = sig_(P[0*256+s*64+lane] + P[1*256+s*64+lane]);
                const float z1  = sig_(P[2*256+s*64+lane] + P[3*256+s*64+lane]);
                const float hn1 = P[5*256+s*64+lane];
                const float nv1 = tanh_(P[4*256+s*64+lane] + r1 * hn1);
                const float hp  = H1b[s*64+lane];
                H1b[s*64+lane] = (1.f - z1) * nv1 + z1 * hp;
            }
        }
        __syncthreads();

        // ---------------- refresh lane-distributed state ----------------
        if (wv < 3) {
            #pragma unroll
            for (int s = 0; s < 4; ++s) hr[s] = H0b[s*64+lane];
        } else if (wv < 9) {
            const float* src = m1 ? H1b : H0b;
            #pragma unroll
            for (int s = 0; s < 4; ++s) hr[s] = src[s*64+lane];
        }
    }

    // ---------------- epilogue ----------------
    if (wv == 0) {
        #pragma unroll
        for (int s = 0; s < 4; ++s) {
            const float hv = H1b[s*64+lane];
            float pa = hv * W[lane];
            float pb = hv * W[HH + lane];
            float pc = hv * fc_w[lane];
            float pd = hv * fc_w[HH + lane];
            #pragma unroll
            for (int off = 32; off >= 1; off >>= 1) {
                pa += __shfl_down(pa, off);
                pb += __shfl_down(pb, off);
                pc += __shfl_down(pc, off);
                pd += __shfl_down(pd, off);
            }
            if (lane == 0) {
                sa[nb + s] = pa; sb[nb + s] = pb;
                hdot[nb + s] = pc; hb[nb + s] = pd;
            }
        }
    } else if (wv >= 9 && relp < (unsigned)(NN * NN)) {
        rel_pair(rel, Wv, sr, ssum, relp);       // tail (22nd pair)
    }
}

// ---------------------------------------------------------------------------
// k2: per row i — masked leaky scores, exact masked-softmax semantics,
// out_i = hdot_i + (sum_j e_j*m_j*hb_j)/denom + fc_b.
// ---------------------------------------------------------------------------
__global__ __launch_bounds__(256)
void k2(const float* __restrict__ sa, const float* __restrict__ sb,
        const float* __restrict__ hdot, const float* __restrict__ hb,
        const float* __restrict__ sr, const float* __restrict__ ssum,
        const float* __restrict__ bscal, const float* __restrict__ fc_b,
        float* __restrict__ out)
{
    __shared__ float red[12];
    const int i   = blockIdx.x;
    const int tid = threadIdx.x;
    const int j4  = tid * 4;
    const float sai = sa[i] + bscal[0];

    const float4 srv = *(const float4*)(sr   + (size_t)i * NN + j4);
    const float4 ssv = *(const float4*)(ssum + (size_t)i * NN + j4);
    const float4 sbv = *(const float4*)(sb + j4);

    float tv[4], mk[4];
    float mloc = -3.4e38f;
    {
        const float srq[4] = {srv.x, srv.y, srv.z, srv.w};
        const float ssq[4] = {ssv.x, ssv.y, ssv.z, ssv.w};
        const float sbq[4] = {sbv.x, sbv.y, sbv.z, sbv.w};
        #pragma unroll
        for (int q = 0; q < 4; ++q) {
            float w = sai + sbq[q] + srq[q];
            w = (w >= 0.0f) ? w : SLOPEV * w;
            const float m = (ssq[q] != 0.0f) ? 1.0f : 0.0f;
            float t = m * w;
            t = (t == 0.0f) ? NEGV : t;
            tv[q] = t; mk[q] = m;
            mloc = fmaxf(mloc, t);
        }
    }
    #pragma unroll
    for (int off = 32; off >= 1; off >>= 1) mloc = fmaxf(mloc, __shfl_xor(mloc, off));
    if ((tid & 63) == 0) red[tid >> 6] = mloc;
    __syncthreads();
    const float mx = fmaxf(fmaxf(red[0], red[1]), fmaxf(red[2], red[3]));

    const float4 hbv = *(const float4*)(hb + j4);
    const float hbq[4] = {hbv.x, hbv.y, hbv.z, hbv.w};
    float sloc = 0.0f, vloc = 0.0f;
    #pragma unroll
    for (int q = 0; q < 4; ++q) {
        const float e = __expf(tv[q] - mx);   // masked -> exp(-1e4 - mx) == 0
        sloc += e;
        vloc += e * mk[q] * hbq[q];
    }
    #pragma unroll
    for (int off = 32; off >= 1; off >>= 1) {
        sloc += __shfl_xor(sloc, off);
        vloc += __shfl_xor(vloc, off);
    }
    if ((tid & 63) == 0) { red[4 + (tid >> 6)] = sloc; red[8 + (tid >> 6)] = vloc; }
    __syncthreads();
    if (tid == 0) {
        const float denom = red[4] + red[5] + red[6] + red[7];
        const float vsum  = red[8] + red[9] + red[10] + red[11];
        out[i] = hdot[i] + vsum / denom + fc_b[0];
    }
}

// ---------------------------------------------------------------------------
extern "C" void kernel_launch(void* const* d_in, const int* in_sizes, int n_in,
                              void* d_out, int out_size, void* d_ws, size_t ws_size,
                              hipStream_t stream)
{
    const float* x     = (const float*)d_in[0];
    const float* rel   = (const float*)d_in[1];
    const float* W     = (const float*)d_in[2];
    const float* b     = (const float*)d_in[3];
    const float* fc_w  = (const float*)d_in[4];
    const float* fc_b  = (const float*)d_in[5];
    const float* Wih0  = (const float*)d_in[6];
    const float* Whh0  = (const float*)d_in[7];
    const float* bih0  = (const float*)d_in[8];
    const float* bhh0  = (const float*)d_in[9];
    const float* Wih1  = (const float*)d_in[10];
    const float* Whh1  = (const float*)d_in[11];
    const float* bih1  = (const float*)d_in[12];
    const float* bhh1  = (const float*)d_in[13];

    float* ws   = (float*)d_ws;
    float* sa   = ws;                         // 1024
    float* sb   = sa   + NN;                  // 1024
    float* hdot = sb   + NN;                  // 1024
    float* hb   = hdot + NN;                  // 1024
    float* sr   = hb   + NN;                  // 1024*1024
    float* ssum = sr   + (size_t)NN * NN;     // 1024*1024

    k_fused<<<256, 768, 0, stream>>>(x, rel, W, fc_w,
                                     Wih0, Whh0, bih0, bhh0,
                                     Wih1, Whh1, bih1, bhh1,
                                     sa, sb, hdot, hb, sr, ssum);
    k2<<<NN, 256, 0, stream>>>(sa, sb, hdot, hb, sr, ssum,
                               b, fc_b, (float*)d_out);
}

// Round 9
// 528.305 us; speedup vs baseline: 2.7225x; 1.0458x over previous
//
#include <hip/hip_runtime.h>
#include <cstddef>

#define NN 1024
#define DD 6
#define TT 60
#define HH 64
#define NEGV  (-10000.0f)
#define SLOPEV (0.01f)

typedef _Float16 h2_t __attribute__((ext_vector_type(2)));

__device__ __forceinline__ float sig_(float x)  { return 1.0f / (1.0f + __expf(-x)); }
__device__ __forceinline__ float tanh_(float x) { return 1.0f - 2.0f / (__expf(2.0f * x) + 1.0f); }
__device__ __forceinline__ float rl_(float v, int l) {
    return __int_as_float(__builtin_amdgcn_readlane(__float_as_int(v), l));
}
__device__ __forceinline__ h2_t bch2_(float v) { return __builtin_bit_cast(h2_t, v); }

__device__ __forceinline__ void rel_pair(const float* __restrict__ rel,
                                         const float* __restrict__ Wv,
                                         float* __restrict__ sr,
                                         float* __restrict__ ssum,
                                         unsigned int relp)
{
    const float4* base = (const float4*)(rel + (size_t)relp * 64);
    float d0 = 0.f, d1 = 0.f, s0 = 0.f, s1 = 0.f;
    #pragma unroll
    for (int c = 0; c < 2; ++c) {
        float4 v[8];
        #pragma unroll
        for (int q = 0; q < 8; ++q) v[q] = base[c * 8 + q];
        #pragma unroll
        for (int q = 0; q < 8; ++q) {
            const float4 wq = ((const float4*)Wv)[c * 8 + q];
            d0 += v[q].x * wq.x + v[q].z * wq.z;
            d1 += v[q].y * wq.y + v[q].w * wq.w;
            s0 += v[q].x + v[q].z;
            s1 += v[q].y + v[q].w;
        }
    }
    sr[relp]   = d0 + d1;
    ssum[relp] = s0 + s1;
}

// ---------------------------------------------------------------------------
// k_fused: 512 blocks x 768 threads (12 waves), 2 samples/block, 2 blocks/CU.
// MM via f16 dot2 (fp32 acc): readlane(packed h) + v_dot2 = 1 inst/MAC.
//   waves 0-2 : L0 gate g. wreg: x(12) + Wih0 row(6) + packed Whh0 row(32).
//   waves 3-8 : L1 (gate g, matrix m). wreg: packed row(32).
//   waves 9-11: rel streaming, 1 pair/thread every 5th iter (13 slots >= 11).
// ONE barrier/step: preacts double-buffered by parity; every GRU wave
// redundantly computes the activations it needs and repacks h in-register
// (2x __shfl + cvt_pkrtz), so there is no serial phase-2 / second barrier.
// ---------------------------------------------------------------------------
__global__ __launch_bounds__(768)
void k_fused(const float* __restrict__ x, const float* __restrict__ rel,
             const float* __restrict__ W, const float* __restrict__ fc_w,
             const float* __restrict__ Wih0, const float* __restrict__ Whh0,
             const float* __restrict__ bih0, const float* __restrict__ bhh0,
             const float* __restrict__ Wih1, const float* __restrict__ Whh1,
             const float* __restrict__ bih1, const float* __restrict__ bhh1,
             float* __restrict__ sa, float* __restrict__ sb,
             float* __restrict__ hdot, float* __restrict__ hb,
             float* __restrict__ sr, float* __restrict__ ssum)
{
    __shared__ float smem[2624];
    // L0B[par][g(4)][s(2)][64] : g = r, z, xn, hn          -> [0, 1024)
    // L1B[par][g(3)][m(2)][s(2)][64]                       -> [1024, 2560)
    // Wv[64]                                               -> [2560, 2624)
    float* L0B = smem;
    float* L1B = smem + 1024;
    float* Wv  = smem + 2560;

    const int tid  = threadIdx.x;
    const int wv   = tid >> 6;
    const int lane = tid & 63;
    const int nb   = blockIdx.x * 2;

    if (tid < 64) Wv[tid] = W[2 * HH + tid];

    float wreg[50];
    float hr2[2];            // packed f16 pairs of the state this wave bcasts
    float hrf[2];            // f32 state at row = lane (for the update eq)
    float b0 = 0.f, b1 = 0.f;
    unsigned int relp = 0xFFFFFFFFu;
    int m1 = 0;

    hr2[0] = hr2[1] = 0.f;
    hrf[0] = hrf[1] = 0.f;

    if (wv < 3) {
        const int row = wv * 64 + lane;
        #pragma unroll
        for (int s = 0; s < 2; ++s)
            #pragma unroll
            for (int d = 0; d < DD; ++d)
                wreg[s * 6 + d] = (lane < TT) ? x[(size_t)(nb + s) * DD * TT + d * TT + lane] : 0.f;
        #pragma unroll
        for (int d = 0; d < DD; ++d) wreg[12 + d] = Wih0[row * DD + d];
        const float2* wr = (const float2*)(Whh0 + (size_t)row * HH);
        #pragma unroll
        for (int q = 0; q < 32; ++q) {
            const float2 p = wr[q];
            wreg[18 + q] = __builtin_bit_cast(float, __builtin_amdgcn_cvt_pkrtz(p.x, p.y));
        }
        b0 = bih0[row]; b1 = bhh0[row];
    } else if (wv < 9) {
        const int u = wv - 3;
        m1 = u & 1;
        const int row = (u >> 1) * 64 + lane;
        const float2* wr = (const float2*)((m1 ? Whh1 : Wih1) + (size_t)row * HH);
        #pragma unroll
        for (int q = 0; q < 32; ++q) {
            const float2 p = wr[q];
            wreg[q] = __builtin_bit_cast(float, __builtin_amdgcn_cvt_pkrtz(p.x, p.y));
        }
        b0 = m1 ? bhh1[row] : bih1[row];
    } else {
        relp = blockIdx.x * 192 + (tid - 576);   // 0..98303, stride 98304
    }
    __syncthreads();

    const int pl2 = 2 * (lane & 31);

    for (int i = 0; i <= TT; ++i) {
        const int par = i & 1;

        // ---------------- MM phase / rel ----------------
        if (wv < 3) {
            if (i < TT) {
                float xg0 = b0, xg1 = b0;
                #pragma unroll
                for (int d = 0; d < DD; ++d) {
                    const float wd = wreg[12 + d];
                    xg0 += rl_(wreg[d], i) * wd;
                    xg1 += rl_(wreg[6 + d], i) * wd;
                }
                float hg0 = b1, hg1 = b1;
                #pragma unroll
                for (int j = 0; j < 32; ++j) {
                    const h2_t wj = bch2_(wreg[18 + j]);
                    hg0 = __builtin_amdgcn_fdot2(bch2_(rl_(hr2[0], j)), wj, hg0, false);
                    hg1 = __builtin_amdgcn_fdot2(bch2_(rl_(hr2[1], j)), wj, hg1, false);
                }
                if (wv < 2) {
                    L0B[((par * 4 + wv) * 2 + 0) * 64 + lane] = xg0 + hg0;
                    L0B[((par * 4 + wv) * 2 + 1) * 64 + lane] = xg1 + hg1;
                } else {
                    L0B[((par * 4 + 2) * 2 + 0) * 64 + lane] = xg0;
                    L0B[((par * 4 + 2) * 2 + 1) * 64 + lane] = xg1;
                    L0B[((par * 4 + 3) * 2 + 0) * 64 + lane] = hg0;
                    L0B[((par * 4 + 3) * 2 + 1) * 64 + lane] = hg1;
                }
            }
        } else if (wv < 9) {
            if (i >= 1) {
                const int u = wv - 3, g = u >> 1;
                float a0 = b0, a1 = b0;
                #pragma unroll
                for (int j = 0; j < 32; ++j) {
                    const h2_t wj = bch2_(wreg[j]);
                    a0 = __builtin_amdgcn_fdot2(bch2_(rl_(hr2[0], j)), wj, a0, false);
                    a1 = __builtin_amdgcn_fdot2(bch2_(rl_(hr2[1], j)), wj, a1, false);
                }
                L1B[(((par * 3 + g) * 2 + m1) * 2 + 0) * 64 + lane] = a0;
                L1B[(((par * 3 + g) * 2 + m1) * 2 + 1) * 64 + lane] = a1;
            }
        } else {
            if ((i % 5 == 0) && relp < (unsigned)(NN * NN)) {
                rel_pair(rel, Wv, sr, ssum, relp);
                relp += 98304;
            }
        }
        __syncthreads();

        // ---------------- redundant activations (no 2nd barrier) ----------------
        if (wv < 9) {
            const bool needs_h0 = (wv < 3) || (m1 == 0 && wv >= 3);
            if (needs_h0 && i < TT) {
                #pragma unroll
                for (int s = 0; s < 2; ++s) {
                    const float r  = sig_(L0B[((par * 4 + 0) * 2 + s) * 64 + lane]);
                    const float z  = sig_(L0B[((par * 4 + 1) * 2 + s) * 64 + lane]);
                    const float xn = L0B[((par * 4 + 2) * 2 + s) * 64 + lane];
                    const float hn = L0B[((par * 4 + 3) * 2 + s) * 64 + lane];
                    const float nv = tanh_(xn + r * hn);
                    const float hnew = (1.f - z) * nv + z * hrf[s];
                    hrf[s] = hnew;
                    const float e0 = __shfl(hnew, pl2);
                    const float e1 = __shfl(hnew, pl2 + 1);
                    hr2[s] = __builtin_bit_cast(float, __builtin_amdgcn_cvt_pkrtz(e0, e1));
                }
            } else if (!needs_h0 && i >= 1) {      // m1 == 1 waves: h1 state
                #pragma unroll
                for (int s = 0; s < 2; ++s) {
                    const float r1 = sig_(L1B[(((par * 3 + 0) * 2 + 0) * 2 + s) * 64 + lane]
                                        + L1B[(((par * 3 + 0) * 2 + 1) * 2 + s) * 64 + lane]);
                    const float z1 = sig_(L1B[(((par * 3 + 1) * 2 + 0) * 2 + s) * 64 + lane]
                                        + L1B[(((par * 3 + 1) * 2 + 1) * 2 + s) * 64 + lane]);
                    const float xn1 = L1B[(((par * 3 + 2) * 2 + 0) * 2 + s) * 64 + lane];
                    const float hn1 = L1B[(((par * 3 + 2) * 2 + 1) * 2 + s) * 64 + lane];
                    const float nv1 = tanh_(xn1 + r1 * hn1);
                    const float hnew = (1.f - z1) * nv1 + z1 * hrf[s];
                    hrf[s] = hnew;
                    const float e0 = __shfl(hnew, pl2);
                    const float e1 = __shfl(hnew, pl2 + 1);
                    hr2[s] = __builtin_bit_cast(float, __builtin_amdgcn_cvt_pkrtz(e0, e1));
                }
            }
        }
    }

    // ---------------- epilogue: wave 4 (g=0,m=1) holds final h1 f32 ----------------
    if (wv == 4) {
        #pragma unroll
        for (int s = 0; s < 2; ++s) {
            const float hv = hrf[s];
            float pa = hv * W[lane];
            float pb = hv * W[HH + lane];
            float pc = hv * fc_w[lane];
            float pd = hv * fc_w[HH + lane];
            #pragma unroll
            for (int off = 32; off >= 1; off >>= 1) {
                pa += __shfl_down(pa, off);
                pb += __shfl_down(pb, off);
                pc += __shfl_down(pc, off);
                pd += __shfl_down(pd, off);
            }
            if (lane == 0) {
                sa[nb + s] = pa; sb[nb + s] = pb;
                hdot[nb + s] = pc; hb[nb + s] = pd;
            }
        }
    }
}

// ---------------------------------------------------------------------------
// k2: per row i — masked leaky scores, exact masked-softmax semantics,
// out_i = hdot_i + (sum_j e_j*m_j*hb_j)/denom + fc_b.
// ---------------------------------------------------------------------------
__global__ __launch_bounds__(256)
void k2(const float* __restrict__ sa, const float* __restrict__ sb,
        const float* __restrict__ hdot, const float* __restrict__ hb,
        const float* __restrict__ sr, const float* __restrict__ ssum,
        const float* __restrict__ bscal, const float* __restrict__ fc_b,
        float* __restrict__ out)
{
    __shared__ float red[12];
    const int i   = blockIdx.x;
    const int tid = threadIdx.x;
    const int j4  = tid * 4;
    const float sai = sa[i] + bscal[0];

    const float4 srv = *(const float4*)(sr   + (size_t)i * NN + j4);
    const float4 ssv = *(const float4*)(ssum + (size_t)i * NN + j4);
    const float4 sbv = *(const float4*)(sb + j4);

    float tv[4], mk[4];
    float mloc = -3.4e38f;
    {
        const float srq[4] = {srv.x, srv.y, srv.z, srv.w};
        const float ssq[4] = {ssv.x, ssv.y, ssv.z, ssv.w};
        const float sbq[4] = {sbv.x, sbv.y, sbv.z, sbv.w};
        #pragma unroll
        for (int q = 0; q < 4; ++q) {
            float w = sai + sbq[q] + srq[q];
            w = (w >= 0.0f) ? w : SLOPEV * w;
            const float m = (ssq[q] != 0.0f) ? 1.0f : 0.0f;
            float t = m * w;
            t = (t == 0.0f) ? NEGV : t;
            tv[q] = t; mk[q] = m;
            mloc = fmaxf(mloc, t);
        }
    }
    #pragma unroll
    for (int off = 32; off >= 1; off >>= 1) mloc = fmaxf(mloc, __shfl_xor(mloc, off));
    if ((tid & 63) == 0) red[tid >> 6] = mloc;
    __syncthreads();
    const float mx = fmaxf(fmaxf(red[0], red[1]), fmaxf(red[2], red[3]));

    const float4 hbv = *(const float4*)(hb + j4);
    const float hbq[4] = {hbv.x, hbv.y, hbv.z, hbv.w};
    float sloc = 0.0f, vloc = 0.0f;
    #pragma unroll
    for (int q = 0; q < 4; ++q) {
        const float e = __expf(tv[q] - mx);   // masked -> exp(-1e4 - mx) == 0
        sloc += e;
        vloc += e * mk[q] * hbq[q];
    }
    #pragma unroll
    for (int off = 32; off >= 1; off >>= 1) {
        sloc += __shfl_xor(sloc, off);
        vloc += __shfl_xor(vloc, off);
    }
    if ((tid & 63) == 0) { red[4 + (tid >> 6)] = sloc; red[8 + (tid >> 6)] = vloc; }
    __syncthreads();
    if (tid == 0) {
        const float denom = red[4] + red[5] + red[6] + red[7];
        const float vsum  = red[8] + red[9] + red[10] + red[11];
        out[i] = hdot[i] + vsum / denom + fc_b[0];
    }
}

// ---------------------------------------------------------------------------
extern "C" void kernel_launch(void* const* d_in, const int* in_sizes, int n_in,
                              void* d_out, int out_size, void* d_ws, size_t ws_size,
                              hipStream_t stream)
{
    const float* x     = (const float*)d_in[0];
    const float* rel   = (const float*)d_in[1];
    const float* W     = (const float*)d_in[2];
    const float* b     = (const float*)d_in[3];
    const float* fc_w  = (const float*)d_in[4];
    const float* fc_b  = (const float*)d_in[5];
    const float* Wih0  = (const float*)d_in[6];
    const float* Whh0  = (const float*)d_in[7];
    const float* bih0  = (const float*)d_in[8];
    const float* bhh0  = (const float*)d_in[9];
    const float* Wih1  = (const float*)d_in[10];
    const float* Whh1  = (const float*)d_in[11];
    const float* bih1  = (const float*)d_in[12];
    const float* bhh1  = (const float*)d_in[13];

    float* ws   = (float*)d_ws;
    float* sa   = ws;                         // 1024
    float* sb   = sa   + NN;                  // 1024
    float* hdot = sb   + NN;                  // 1024
    float* hb   = hdot + NN;                  // 1024
    float* sr   = hb   + NN;                  // 1024*1024
    float* ssum = sr   + (size_t)NN * NN;     // 1024*1024

    k_fused<<<512, 768, 0, stream>>>(x, rel, W, fc_w,
                                     Wih0, Whh0, bih0, bhh0,
                                     Wih1, Whh1, bih1, bhh1,
                                     sa, sb, hdot, hb, sr, ssum);
    k2<<<NN, 256, 0, stream>>>(sa, sb, hdot, hb, sr, ssum,
                               b, fc_b, (float*)d_out);
}